// Round 1
// baseline (134161.340 us; speedup 1.0000x reference)
//
#include <hip/hip_runtime.h>
#include <math.h>

#define Tn   16384
#define Mg   200
#define Nc   6
#define TOT  1200
#define Kk   25
#define Din  784

// ---------------------------------------------------------------- transpose
__global__ void transpose_k(const float* __restrict__ src, float* __restrict__ dst,
                            int R, int C) {
    __shared__ float tile[32][33];
    int bx = blockIdx.x * 32, by = blockIdx.y * 32;
    int x = bx + threadIdx.x;
    for (int j = 0; j < 32; j += 8) {
        int y = by + threadIdx.y + j;
        if (x < C && y < R) tile[threadIdx.y + j][threadIdx.x] = src[(size_t)y * C + x];
    }
    __syncthreads();
    int x2 = by + threadIdx.x;
    for (int j = 0; j < 32; j += 8) {
        int y2 = bx + threadIdx.y + j;
        if (x2 < R && y2 < C) dst[(size_t)y2 * R + x2] = tile[threadIdx.x][threadIdx.y + j];
    }
}

// ------------------------------------------------- Za = X @ Wa^T + ba  (16384 x 200)
__global__ void za_k(const float* __restrict__ X, const float* __restrict__ Wa,
                     const float* __restrict__ ba, float* __restrict__ Za) {
    __shared__ float xs[16][788];            // padded row (788*4 % 16 == 0)
    const int tid = threadIdx.x;
    const int t0  = blockIdx.x * 16;
    for (int idx = tid; idx < 16 * Din; idx += 256) {
        int tt = idx / Din, kk = idx - tt * Din;
        xs[tt][kk] = X[(size_t)(t0 + tt) * Din + kk];
    }
    __syncthreads();
    const int tq = tid & 15, gq = tid >> 4;
    const float4* xrow = reinterpret_cast<const float4*>(&xs[tq][0]);
    for (int g = gq; g < Mg; g += 16) {
        float acc = ba[g];
        const float4* wrow = reinterpret_cast<const float4*>(Wa + (size_t)g * Din);
        for (int k4 = 0; k4 < Din / 4; ++k4) {
            float4 a = xrow[k4], b = wrow[k4];
            acc = fmaf(a.x, b.x, acc); acc = fmaf(a.y, b.y, acc);
            acc = fmaf(a.z, b.z, acc); acc = fmaf(a.w, b.w, acc);
        }
        Za[(size_t)(t0 + tq) * Mg + g] = acc;
    }
}

// ------------------------------------------------------------- serial recurrence
// One persistent workgroup. State in LDS: u = Wb@psi (unnormalized), psi (==phi), alpha.
__launch_bounds__(640, 1)
__global__ void serial_k(const float* __restrict__ Za, const float* __restrict__ WbT,
                         const float* __restrict__ bb,
                         float* __restrict__ Yval, int* __restrict__ Yidx,
                         float* __restrict__ outTail) {
    __shared__ float u[TOT], psi[TOT], bbs[TOT], sig[TOT];
    __shared__ float zas[2][Mg];
    __shared__ float lam[Mg];
    __shared__ int   js[Mg];
    __shared__ int   rnk[Mg];
    __shared__ float red[16];
    __shared__ float alpha_s, minv;
    __shared__ int   sel_e[Kk];
    __shared__ float sel_d[Kk];

    const int tid = threadIdx.x;
    const int i0  = 2 * tid;                 // owns {i0, i0+1} when tid < 600

    if (tid < 600) {
        u[i0] = 0.f; u[i0 + 1] = 0.f;
        psi[i0] = 0.f; psi[i0 + 1] = 0.f;
        bbs[i0] = bb[i0]; bbs[i0 + 1] = bb[i0 + 1];
    }
    if (tid < Mg) zas[0][tid] = Za[tid];
    if (tid == 639) alpha_s = 0.f;
    __syncthreads();

    const int g0 = i0 / Nc, g1 = (i0 + 1) / Nc;

    for (int t = 0; t < Tn; ++t) {
        const int p = t & 1;
        // ---- phase 1: sigma = u/alpha + bb + za, local min
        float a = alpha_s;
        float inv = (a == 0.f) ? 1.f : (1.f / a);
        float lmin = INFINITY;
        if (tid < 600) {
            float s0 = fmaf(u[i0],     inv, bbs[i0]     + zas[p][g0]);
            float s1 = fmaf(u[i0 + 1], inv, bbs[i0 + 1] + zas[p][g1]);
            sig[i0] = s0; sig[i0 + 1] = s1;
            lmin = fminf(s0, s1);
        }
        for (int o = 32; o; o >>= 1) lmin = fminf(lmin, __shfl_down(lmin, o));
        if ((tid & 63) == 0) red[tid >> 6] = lmin;
        __syncthreads();
        // ---- phase 2: global min
        if (tid == 0) {
            float m = red[0];
            for (int w = 1; w < 10; ++w) m = fminf(m, red[w]);
            minv = m;
        }
        __syncthreads();
        // ---- phase 3: pi, per-group max/argmax
        if (tid < Mg) {
            const int b = Nc * tid;
            const float m1 = 1.f - minv;
            float best = -INFINITY; int bj = 0;
            #pragma unroll
            for (int j = 0; j < Nc; ++j) {
                float pv = (1.f - psi[b + j]) * (sig[b + j] + m1);
                if (pv > best) { best = pv; bj = j; }
            }
            lam[tid] = best; js[tid] = bj; rnk[tid] = 0;
        }
        __syncthreads();
        // ---- phase 4: rank-based top-K (200x200 cmps over 600 threads)
        if (tid < 600) {
            const int g = tid % Mg, seg = tid / Mg;
            const int h0 = seg * 67, h1 = (seg == 2) ? Mg : h0 + 67;
            const float Lg = lam[g];
            int r = 0;
            for (int h = h0; h < h1; ++h) {
                float Lh = lam[h];
                r += (Lh > Lg) || (Lh == Lg && h < g);
            }
            if (r) atomicAdd(&rnk[g], r);
        }
        __syncthreads();
        // ---- phase 5: selected groups -> y, delta, output pairs
        if (tid < Mg) {
            int r = rnk[tid];
            if (r < Kk) {
                int pos = Nc * tid + js[tid];
                float y  = tanhf(sig[pos]);
                Yval[(size_t)t * Kk + r] = fmaxf(y, 0.f);
                Yidx[(size_t)t * Kk + r] = tid;
                float d = y - 0.5f * psi[pos];
                sel_e[r] = pos;
                sel_d[r] = (d > 0.f) ? d : 0.f;
            }
        }
        __syncthreads();
        // ---- phase 6a: psi decay; issue za prefetch
        float zpre = 0.f;
        if (t + 1 < Tn && tid < Mg) zpre = Za[(size_t)(t + 1) * Mg + tid];
        if (tid < 600) { psi[i0] *= 0.5f; psi[i0 + 1] *= 0.5f; }
        __syncthreads();
        // ---- phase 6b/7: psi scatter, alpha update, u column update
        if (tid < Mg && rnk[tid] < Kk) {
            float d = sel_d[rnk[tid]];
            if (d > 0.f) psi[sel_e[rnk[tid]]] += d;
        }
        if (tid == 639) {
            float s = 0.f;
            for (int k = 0; k < Kk; ++k) s += sel_d[k];
            alpha_s = 0.5f * alpha_s + s;
        }
        if (tid < 600) {
            float u0 = 0.5f * u[i0], u1 = 0.5f * u[i0 + 1];
            for (int k = 0; k < Kk; ++k) {
                float d = sel_d[k];                     // LDS broadcast, wave-uniform
                if (d != 0.f) {
                    const float* col = WbT + (size_t)sel_e[k] * TOT + i0;
                    u0 = fmaf(d, col[0], u0);
                    u1 = fmaf(d, col[1], u1);
                }
            }
            u[i0] = u0; u[i0 + 1] = u1;
        }
        if (t + 1 < Tn && tid < Mg) zas[(t + 1) & 1][tid] = zpre;
        __syncthreads();
    }
    // ---- epilogue: x_b, phi, psi
    if (tid < 600) {
        float a = alpha_s;
        float inv = (a == 0.f) ? 1.f : (1.f / a);
        float p0 = psi[i0], p1 = psi[i0 + 1];
        outTail[i0] = p0 * inv;            outTail[i0 + 1] = p1 * inv;
        outTail[TOT + i0] = p0;            outTail[TOT + i0 + 1] = p1;
        outTail[2 * TOT + i0] = p0;        outTail[2 * TOT + i0 + 1] = p1;
    }
}

// ------------------------------------------------- preds = bd + sum val * WdT[idx]
__global__ void preds_k(const float* __restrict__ Yval, const int* __restrict__ Yidx,
                        const float* __restrict__ WdT, const float* __restrict__ bd,
                        float* __restrict__ out) {
    const int t = blockIdx.x;
    __shared__ float sv[Kk];
    __shared__ int   si[Kk];
    if (threadIdx.x < Kk) {
        sv[threadIdx.x] = Yval[(size_t)t * Kk + threadIdx.x];
        si[threadIdx.x] = Yidx[(size_t)t * Kk + threadIdx.x];
    }
    __syncthreads();
    for (int d = threadIdx.x; d < Din; d += 256) {
        float acc = bd[d];
        #pragma unroll
        for (int k = 0; k < Kk; ++k)
            acc = fmaf(sv[k], WdT[(size_t)si[k] * Din + d], acc);
        out[(size_t)t * Din + d] = acc;
    }
}

extern "C" void kernel_launch(void* const* d_in, const int* in_sizes, int n_in,
                              void* d_out, int out_size, void* d_ws, size_t ws_size,
                              hipStream_t stream) {
    const float* X  = (const float*)d_in[0];
    const float* Wa = (const float*)d_in[1];
    const float* ba = (const float*)d_in[2];
    const float* Wb = (const float*)d_in[3];
    const float* bb = (const float*)d_in[4];
    const float* Wd = (const float*)d_in[5];
    const float* bd = (const float*)d_in[6];
    float* out = (float*)d_out;

    float* w    = (float*)d_ws;
    float* Za   = w;                                   // 16384*200
    float* WbT  = Za  + (size_t)Tn * Mg;               // 1200*1200
    float* WdT  = WbT + (size_t)TOT * TOT;             // 200*784
    float* Yv   = WdT + (size_t)Mg * Din;              // 16384*25
    int*   Yi   = (int*)(Yv + (size_t)Tn * Kk);        // 16384*25

    dim3 tb(32, 8);
    transpose_k<<<dim3((TOT + 31) / 32, (TOT + 31) / 32), tb, 0, stream>>>(Wb, WbT, TOT, TOT);
    transpose_k<<<dim3((Mg + 31) / 32, (Din + 31) / 32), tb, 0, stream>>>(Wd, WdT, Din, Mg);
    za_k<<<Tn / 16, 256, 0, stream>>>(X, Wa, ba, Za);
    serial_k<<<1, 640, 0, stream>>>(Za, WbT, bb, Yv, Yi, out + (size_t)Tn * Din);
    preds_k<<<Tn, 256, 0, stream>>>(Yv, Yi, WdT, bd, out);
}

// Round 2
// 78026.862 us; speedup vs baseline: 1.7194x; 1.7194x over previous
//
#include <hip/hip_runtime.h>
#include <math.h>

#define Tn   16384
#define Mg   200
#define Nc   6
#define TOT  1200
#define Kk   25
#define Din  784

// ---------------------------------------------------------------- transpose
__global__ void transpose_k(const float* __restrict__ src, float* __restrict__ dst,
                            int R, int C) {
    __shared__ float tile[32][33];
    int bx = blockIdx.x * 32, by = blockIdx.y * 32;
    int x = bx + threadIdx.x;
    for (int j = 0; j < 32; j += 8) {
        int y = by + threadIdx.y + j;
        if (x < C && y < R) tile[threadIdx.y + j][threadIdx.x] = src[(size_t)y * C + x];
    }
    __syncthreads();
    int x2 = by + threadIdx.x;
    for (int j = 0; j < 32; j += 8) {
        int y2 = bx + threadIdx.y + j;
        if (x2 < R && y2 < C) dst[(size_t)y2 * R + x2] = tile[threadIdx.x][threadIdx.y + j];
    }
}

// ------------------------------------------------- Za = X @ Wa^T + ba  (16384 x 200)
__global__ void za_k(const float* __restrict__ X, const float* __restrict__ Wa,
                     const float* __restrict__ ba, float* __restrict__ Za) {
    __shared__ float xs[16][788];
    const int tid = threadIdx.x;
    const int t0  = blockIdx.x * 16;
    for (int idx = tid; idx < 16 * Din; idx += 256) {
        int tt = idx / Din, kk = idx - tt * Din;
        xs[tt][kk] = X[(size_t)(t0 + tt) * Din + kk];
    }
    __syncthreads();
    const int tq = tid & 15, gq = tid >> 4;
    const float4* xrow = reinterpret_cast<const float4*>(&xs[tq][0]);
    for (int g = gq; g < Mg; g += 16) {
        float acc = ba[g];
        const float4* wrow = reinterpret_cast<const float4*>(Wa + (size_t)g * Din);
        for (int k4 = 0; k4 < Din / 4; ++k4) {
            float4 a = xrow[k4], b = wrow[k4];
            acc = fmaf(a.x, b.x, acc); acc = fmaf(a.y, b.y, acc);
            acc = fmaf(a.z, b.z, acc); acc = fmaf(a.w, b.w, acc);
        }
        Za[(size_t)(t0 + tq) * Mg + g] = acc;
    }
}

// ------------------------------------------------------------- serial recurrence
// Owner-register design: thread g (<200) holds its group's u[6], psi[6], bb[6],
// sigma[6] in registers. LDS only for: rank keys, min-reduce, selected deltas.
// 3 barriers/step. u = Wb@psi tracked incrementally: u' = 0.5u + sum d_k * Wb[:,e_k].
__launch_bounds__(256, 1)
__global__ void serial_k(const float* __restrict__ Za, const float* __restrict__ WbT,
                         const float* __restrict__ bb,
                         float* __restrict__ Yval, int* __restrict__ Yidx,
                         float* __restrict__ outTail) {
    __shared__ alignas(16) unsigned long long lamk[Mg];
    __shared__ alignas(16) float red[4];
    __shared__ float sel_d[Kk];
    __shared__ int   sel_o[Kk];    // element index * TOT (column offset)

    const int tid = threadIdx.x;
    const bool own = (tid < Mg);
    const int b = Nc * tid;

    float u0=0.f,u1=0.f,u2=0.f,u3=0.f,u4=0.f,u5=0.f;
    float p0=0.f,p1=0.f,p2=0.f,p3=0.f,p4=0.f,p5=0.f;
    float b0=0.f,b1=0.f,b2=0.f,b3=0.f,b4=0.f,b5=0.f;
    float alpha = 0.f;
    float zb = 0.f;
    if (own) {
        b0=bb[b]; b1=bb[b+1]; b2=bb[b+2]; b3=bb[b+3]; b4=bb[b+4]; b5=bb[b+5];
        zb = Za[tid];
    }

    for (int t = 0; t < Tn; ++t) {
        // ---- A: sigma (registers), wave-min, cross-wave via red[4]
        float inv = (alpha == 0.f) ? 1.f : (1.f / alpha);
        float s0=0,s1=0,s2=0,s3=0,s4=0,s5=0;
        float lmin = INFINITY;
        if (own) {
            float c = zb;
            s0 = fmaf(u0, inv, b0 + c); s1 = fmaf(u1, inv, b1 + c);
            s2 = fmaf(u2, inv, b2 + c); s3 = fmaf(u3, inv, b3 + c);
            s4 = fmaf(u4, inv, b4 + c); s5 = fmaf(u5, inv, b5 + c);
            lmin = fminf(fminf(fminf(s0,s1),fminf(s2,s3)),fminf(s4,s5));
        }
        for (int o = 32; o; o >>= 1) lmin = fminf(lmin, __shfl_down(lmin, o));
        if ((tid & 63) == 0) red[tid >> 6] = lmin;
        __syncthreads();

        // prefetch next za (long-latency, consumed next iteration)
        float zn = 0.f;
        if (own && t + 1 < Tn) zn = Za[(size_t)(t + 1) * Mg + tid];

        // ---- B: global min, pi, per-group argmax, sortable key
        unsigned long long myk = 0ull;
        float sb = 0.f, pb = 0.f;
        int bj = 0;
        if (own) {
            float4 r4 = *reinterpret_cast<const float4*>(red);
            float m1 = 1.f - fminf(fminf(r4.x, r4.y), fminf(r4.z, r4.w));
            float best = -INFINITY;
            float sa[6] = {s0,s1,s2,s3,s4,s5};
            float pa[6] = {p0,p1,p2,p3,p4,p5};
            #pragma unroll
            for (int j = 0; j < Nc; ++j) {
                float pv = (1.f - pa[j]) * (sa[j] + m1);
                if (pv > best) { best = pv; bj = j; sb = sa[j]; pb = pa[j]; }
            }
            unsigned int ub = __float_as_uint(best);
            ub ^= (unsigned int)(((int)ub) >> 31) | 0x80000000u;
            myk = ((unsigned long long)ub << 32) | (unsigned long long)(0xFFFFFFFFu - (unsigned)tid);
            lamk[tid] = myk;
        }
        __syncthreads();

        // ---- C/D: branch-free rank scan (u64 keys), selection, psi update
        float d = 0.f;
        if (own) {
            int r = 0;
            const ulonglong2* L = reinterpret_cast<const ulonglong2*>(lamk);
            #pragma unroll
            for (int q = 0; q < Mg / 2; ++q) {
                ulonglong2 kv = L[q];
                r += (kv.x > myk) + (kv.y > myk);
            }
            if (r < Kk) {
                float y = tanhf(sb);
                d = y - 0.5f * pb;
                d = (d > 0.f) ? d : 0.f;
                sel_d[r] = d;
                sel_o[r] = (b + bj) * TOT;
                Yval[(size_t)t * Kk + r] = fmaxf(y, 0.f);
                Yidx[(size_t)t * Kk + r] = tid;
            }
            p0 = 0.5f*p0 + ((bj==0)?d:0.f); p1 = 0.5f*p1 + ((bj==1)?d:0.f);
            p2 = 0.5f*p2 + ((bj==2)?d:0.f); p3 = 0.5f*p3 + ((bj==3)?d:0.f);
            p4 = 0.5f*p4 + ((bj==4)?d:0.f); p5 = 0.5f*p5 + ((bj==5)?d:0.f);
        }
        __syncthreads();

        // ---- E: unconditional fully-unrolled 25-column gather + alpha
        if (own) {
            float sd_[Kk]; int so_[Kk];
            #pragma unroll
            for (int k = 0; k < Kk; ++k) { sd_[k] = sel_d[k]; so_[k] = sel_o[k]; }
            float asum = 0.f;
            #pragma unroll
            for (int k = 0; k < Kk; ++k) asum += sd_[k];
            alpha = 0.5f * alpha + asum;

            float a0=0.5f*u0, a1=0.5f*u1, a2=0.5f*u2, a3=0.5f*u3, a4=0.5f*u4, a5=0.5f*u5;
            #pragma unroll
            for (int k = 0; k < Kk; ++k) {
                const float* c = WbT + so_[k] + b;
                float2 x0 = *reinterpret_cast<const float2*>(c);
                float2 x1 = *reinterpret_cast<const float2*>(c + 2);
                float2 x2 = *reinterpret_cast<const float2*>(c + 4);
                float dk = sd_[k];
                a0 = fmaf(dk, x0.x, a0); a1 = fmaf(dk, x0.y, a1);
                a2 = fmaf(dk, x1.x, a2); a3 = fmaf(dk, x1.y, a3);
                a4 = fmaf(dk, x2.x, a4); a5 = fmaf(dk, x2.y, a5);
            }
            u0=a0; u1=a1; u2=a2; u3=a3; u4=a4; u5=a5;
            zb = zn;
        }
    }

    // ---- epilogue: x_b, phi, psi
    if (own) {
        float inv = (alpha == 0.f) ? 1.f : (1.f / alpha);
        float pa[6] = {p0,p1,p2,p3,p4,p5};
        #pragma unroll
        for (int j = 0; j < Nc; ++j) {
            outTail[b + j]           = pa[j] * inv;
            outTail[TOT + b + j]     = pa[j];
            outTail[2 * TOT + b + j] = pa[j];
        }
    }
}

// ------------------------------------------------- preds = bd + sum val * WdT[idx]
__global__ void preds_k(const float* __restrict__ Yval, const int* __restrict__ Yidx,
                        const float* __restrict__ WdT, const float* __restrict__ bd,
                        float* __restrict__ out) {
    const int t = blockIdx.x;
    __shared__ float sv[Kk];
    __shared__ int   si[Kk];
    if (threadIdx.x < Kk) {
        sv[threadIdx.x] = Yval[(size_t)t * Kk + threadIdx.x];
        si[threadIdx.x] = Yidx[(size_t)t * Kk + threadIdx.x];
    }
    __syncthreads();
    for (int d = threadIdx.x; d < Din; d += 256) {
        float acc = bd[d];
        #pragma unroll
        for (int k = 0; k < Kk; ++k)
            acc = fmaf(sv[k], WdT[(size_t)si[k] * Din + d], acc);
        out[(size_t)t * Din + d] = acc;
    }
}

extern "C" void kernel_launch(void* const* d_in, const int* in_sizes, int n_in,
                              void* d_out, int out_size, void* d_ws, size_t ws_size,
                              hipStream_t stream) {
    const float* X  = (const float*)d_in[0];
    const float* Wa = (const float*)d_in[1];
    const float* ba = (const float*)d_in[2];
    const float* Wb = (const float*)d_in[3];
    const float* bb = (const float*)d_in[4];
    const float* Wd = (const float*)d_in[5];
    const float* bd = (const float*)d_in[6];
    float* out = (float*)d_out;

    float* w    = (float*)d_ws;
    float* Za   = w;                                   // 16384*200
    float* WbT  = Za  + (size_t)Tn * Mg;               // 1200*1200
    float* WdT  = WbT + (size_t)TOT * TOT;             // 200*784
    float* Yv   = WdT + (size_t)Mg * Din;              // 16384*25
    int*   Yi   = (int*)(Yv + (size_t)Tn * Kk);        // 16384*25

    dim3 tb(32, 8);
    transpose_k<<<dim3((TOT + 31) / 32, (TOT + 31) / 32), tb, 0, stream>>>(Wb, WbT, TOT, TOT);
    transpose_k<<<dim3((Mg + 31) / 32, (Din + 31) / 32), tb, 0, stream>>>(Wd, WdT, Din, Mg);
    za_k<<<Tn / 16, 256, 0, stream>>>(X, Wa, ba, Za);
    serial_k<<<1, 256, 0, stream>>>(Za, WbT, bb, Yv, Yi, out + (size_t)Tn * Din);
    preds_k<<<Tn, 256, 0, stream>>>(Yv, Yi, WdT, bd, out);
}